// Round 7
// baseline (35.858 us; speedup 1.0000x reference)
//
#include <hip/hip_runtime.h>

#define NUM_POINTS 2048
#define FEAT 512
#define BATCH 32
#define POS_PER_BLOCK 2   // 2 positions x 2 M-split waves = 4 waves/block

using v8s = __attribute__((ext_vector_type(8))) short;
using v4f = __attribute__((ext_vector_type(4))) float;

// fp32 -> bf16 round-to-nearest-even
static __device__ __forceinline__ short f2bf(float x) {
  unsigned u = __float_as_uint(x);
  u += 0x7FFFu + ((u >> 16) & 1u);
  return (short)(u >> 16);
}

// Fused kernel, max-concurrency schedule:
//   1) issue 16 glf float4 loads (oldest in vmcnt order -> retire first)
//   2) issue ALL 32 W1 dwordx4 loads (48 VMEM in flight per thread)
//   3) convert glf -> bf16 B-fragments in LDS (overlaps A-stream latency)
//   4) barrier; consume-only MFMA loop (no loads inside)
//   5) h1 -> LDS (aliases bfrag), 32->8->3 tail
__global__ void __launch_bounds__(256, 2) fcdec_fused(
    const float* __restrict__ glf,
    const float* __restrict__ W1, const float* __restrict__ b1,
    const float* __restrict__ W2, const float* __restrict__ b2,
    const float* __restrict__ W3, const float* __restrict__ b3,
    float* __restrict__ out) {
  __shared__ char smem[32768];
  short* bfrag = (short*)smem;                       // [16 ks][2 nt][64 l][8 j]
  float (*h1s)[32][33] = (float (*)[32][33])smem;    // aliases bfrag (after barrier)

  const int t = threadIdx.x;
  const int w = t >> 6;
  const int l = t & 63;
  const int lp = w >> 1;            // position within block
  const int mt = w & 1;             // M-split
  const int p = blockIdx.x * POS_PER_BLOCK + lp;
  const int lrow = l & 15;
  const int lk = (l >> 4) << 3;     // 0,8,16,24

  // ---- 1: glf loads first (coalesced; 64KB per block, L2-hot) ----
  float4 g[16];
  #pragma unroll
  for (int rep = 0; rep < 16; ++rep) {
    const int c = rep * 256 + t;
    const int b = c >> 7;
    const int k0 = (c & 127) << 2;
    g[rep] = *(const float4*)(glf + b * FEAT + k0);
  }

  // ---- 2: ALL W1 loads for this wave's 16-row slab, one go ----
  const float* A0 = W1 + ((size_t)p * 32u + mt * 16 + lrow) * FEAT + lk;
  float4 fa[16], fb[16];
  #pragma unroll
  for (int ks = 0; ks < 16; ++ks) {
    fa[ks] = *(const float4*)(A0 + ks * 32);
    fb[ks] = *(const float4*)(A0 + ks * 32 + 4);
  }

  // ---- 3: build B fragments in LDS (waits only on glf loads) ----
  // frag layout: lane l holds B[k=ks*32+(l>>4)*8+j][col=nt*16+(l&15)]
  #pragma unroll
  for (int rep = 0; rep < 16; ++rep) {
    const int c = rep * 256 + t;
    const int b = c >> 7;
    const int k0 = (c & 127) << 2;
    const int ks = k0 >> 5;
    const int gsel = (k0 >> 3) & 3;
    const int j0 = k0 & 7;          // 0 or 4
    const int nt = b >> 4;
    const int ll = gsel * 16 + (b & 15);
    short* dst = bfrag + (((ks * 2 + nt) * 64 + ll) << 3) + j0;
    dst[0] = f2bf(g[rep].x); dst[1] = f2bf(g[rep].y);
    dst[2] = f2bf(g[rep].z); dst[3] = f2bf(g[rep].w);
  }
  __syncthreads();

  // ---- 4: consume-only main loop: K=512, 2 MFMA/ks ----
  v4f acc0 = {}, acc1 = {};
  #pragma unroll
  for (int ks = 0; ks < 16; ++ks) {
    v8s a;
    a[0] = f2bf(fa[ks].x); a[1] = f2bf(fa[ks].y);
    a[2] = f2bf(fa[ks].z); a[3] = f2bf(fa[ks].w);
    a[4] = f2bf(fb[ks].x); a[5] = f2bf(fb[ks].y);
    a[6] = f2bf(fb[ks].z); a[7] = f2bf(fb[ks].w);
    v8s bv0 = *(const v8s*)(bfrag + (((ks * 2 + 0) * 64 + l) << 3));
    v8s bv1 = *(const v8s*)(bfrag + (((ks * 2 + 1) * 64 + l) << 3));
    acc0 = __builtin_amdgcn_mfma_f32_16x16x32_bf16(a, bv0, acc0, 0, 0, 0);
    acc1 = __builtin_amdgcn_mfma_f32_16x16x32_bf16(a, bv1, acc1, 0, 0, 0);
  }

  __syncthreads();   // all bfrag reads done before h1s overwrites the region

  // ---- 5: h1 = acc + b1 -> LDS. C/D: lane l holds C[row=(l>>4)*4+r][col=l&15]
  #pragma unroll
  for (int r = 0; r < 4; ++r) {
    const int o = mt * 16 + ((l >> 4) << 2) + r;
    const float bb = b1[p * 32 + o];
    h1s[lp][o][lrow] = acc0[r] + bb;
    h1s[lp][o][16 + lrow] = acc1[r] + bb;
  }
  __syncthreads();

  // ---- Layers 2+3 fp32: one thread per (position-in-block, batch) ----
  if (t < POS_PER_BLOCK * BATCH) {
    const int tp = t >> 5;
    const int b = t & 31;
    const int pg = blockIdx.x * POS_PER_BLOCK + tp;
    float h2[8];
    #pragma unroll
    for (int o8 = 0; o8 < 8; ++o8) {
      float s = b2[pg * 8 + o8];
      const float* w2 = W2 + (size_t)(pg * 8 + o8) * 32;
      #pragma unroll
      for (int i = 0; i < 32; ++i) s += w2[i] * h1s[tp][i][b];
      h2[o8] = s;
    }
    #pragma unroll
    for (int c = 0; c < 3; ++c) {
      float s = b3[pg * 3 + c];
      const float* w3 = W3 + (size_t)(pg * 3 + c) * 8;
      #pragma unroll
      for (int j = 0; j < 8; ++j) s += w3[j] * h2[j];
      out[(size_t)(b * 3 + c) * NUM_POINTS + pg] = s;
    }
  }
}

extern "C" void kernel_launch(void* const* d_in, const int* in_sizes, int n_in,
                              void* d_out, int out_size, void* d_ws, size_t ws_size,
                              hipStream_t stream) {
  const float* glf = (const float*)d_in[0];
  const float* W1  = (const float*)d_in[1];
  const float* b1  = (const float*)d_in[2];
  const float* W2  = (const float*)d_in[3];
  const float* b2  = (const float*)d_in[4];
  const float* W3  = (const float*)d_in[5];
  const float* b3  = (const float*)d_in[6];
  float* out = (float*)d_out;

  hipLaunchKernelGGL(fcdec_fused, dim3(NUM_POINTS / POS_PER_BLOCK), dim3(256), 0, stream,
                     glf, W1, b1, W2, b2, W3, b3, out);
}

// Round 8
// 35.031 us; speedup vs baseline: 1.0236x; 1.0236x over previous
//
#include <hip/hip_runtime.h>

#define NUM_POINTS 2048
#define FEAT 512
#define BATCH 32
#define POS_PER_BLOCK 2   // 2 positions x 2 M-split waves = 4 waves/block

using v8s = __attribute__((ext_vector_type(8))) short;
using v4f = __attribute__((ext_vector_type(4))) float;

typedef __attribute__((address_space(3))) float lds_f;
typedef const __attribute__((address_space(1))) float gbl_f;

// fp32 -> bf16 round-to-nearest-even
static __device__ __forceinline__ short f2bf(float x) {
  unsigned u = __float_as_uint(x);
  u += 0x7FFFu + ((u >> 16) & 1u);
  return (short)(u >> 16);
}

// Pack glf (fp32 [32][512]) into bf16 MFMA B-fragments in ws (proven R1/R3).
// lane l holds B[k = ks*32 + (l>>4)*8 + j][col = nt*16 + (l&15)], j=0..7
__global__ void build_bfrag(const float* __restrict__ glf, short* __restrict__ frag) {
  int i = blockIdx.x * 256 + threadIdx.x;  // 0..16383
  int j = i & 7;
  int l = (i >> 3) & 63;
  int nt = (i >> 9) & 1;
  int ks = i >> 10;
  int b = nt * 16 + (l & 15);
  int k = ks * 32 + ((l >> 4) << 3) + j;
  frag[i] = f2bf(glf[b * FEAT + k]);
}

// DUAL-POOL experiment: lower-K (0..255) via register loads (VGPR-return
// pool), upper-K (256..511) via global_load_lds DMA (LDS-return pool),
// both streams in flight from t=0. Each wave DMA-stages exactly the rows
// it consumes -> no mid-kernel barrier; pure counted-vmcnt dataflow.
// Upper tile XOR-swizzled: source chunk = l ^ (row&7), linear LDS dest,
// read physical chunk = logical ^ (lrow&7)  (involution, rule #21).
__global__ void __launch_bounds__(256, 2) fcdec_main(
    const float* __restrict__ W1, const float* __restrict__ b1,
    const float* __restrict__ W2, const float* __restrict__ b2,
    const float* __restrict__ W3, const float* __restrict__ b3,
    const short* __restrict__ bfrag, float* __restrict__ out) {
  __shared__ float Ahalf[POS_PER_BLOCK][32][256];   // 64 KB upper-K tile
  float* smem_f = &Ahalf[0][0][0];
  float (*h1s)[32][33] = (float (*)[32][33])smem_f; // aliases Ahalf (barrier-separated)

  const int t = threadIdx.x;
  const int w = t >> 6;
  const int l = t & 63;
  const int lp = w >> 1;            // position within block
  const int mt = w & 1;             // M-split
  const int p = blockIdx.x * POS_PER_BLOCK + lp;
  const int lrow = l & 15;
  const int g = l >> 4;             // 0..3
  const int lk = g << 3;            // 0,8,16,24
  const int s = lrow & 7;           // read-side swizzle key

  // ---- Pool 1: register loads, lower-K (k 0..255) ----
  const float* A0 = W1 + ((size_t)p * 32u + mt * 16 + lrow) * FEAT + lk;
  float4 fa[8], fb[8];
  #pragma unroll
  for (int ks = 0; ks < 8; ++ks) {
    fa[ks] = *(const float4*)(A0 + ks * 32);
    fb[ks] = *(const float4*)(A0 + ks * 32 + 4);
  }

  // ---- B fragments, lower half (L2-hot ws) ----
  v8s bl[8][2];
  #pragma unroll
  for (int ks = 0; ks < 8; ++ks) {
    bl[ks][0] = *(const v8s*)(bfrag + (((ks * 2 + 0) * 64 + l) << 3));
    bl[ks][1] = *(const v8s*)(bfrag + (((ks * 2 + 1) * 64 + l) << 3));
  }

  // ---- Pool 2: DMA stage upper-K (k 256..511) of this wave's 16 rows ----
  #pragma unroll
  for (int i = 0; i < 16; ++i) {
    const int r = mt * 16 + i;                    // row within position slab
    gbl_f* src = (gbl_f*)(W1 + ((size_t)p * 32u + r) * FEAT + 256
                          + ((l ^ (r & 7)) << 2));
    lds_f* dst = (lds_f*)&Ahalf[lp][r][0];
    __builtin_amdgcn_global_load_lds(src, dst, 16, 0, 0);
  }

  // ---- B fragments, upper half ----
  v8s bu[8][2];
  #pragma unroll
  for (int ks = 0; ks < 8; ++ks) {
    bu[ks][0] = *(const v8s*)(bfrag + ((((ks + 8) * 2 + 0) * 64 + l) << 3));
    bu[ks][1] = *(const v8s*)(bfrag + ((((ks + 8) * 2 + 1) * 64 + l) << 3));
  }

  // ---- Compute lower-K from registers ----
  v4f acc0 = {}, acc1 = {};
  #pragma unroll
  for (int ks = 0; ks < 8; ++ks) {
    v8s a;
    a[0] = f2bf(fa[ks].x); a[1] = f2bf(fa[ks].y);
    a[2] = f2bf(fa[ks].z); a[3] = f2bf(fa[ks].w);
    a[4] = f2bf(fb[ks].x); a[5] = f2bf(fb[ks].y);
    a[6] = f2bf(fb[ks].z); a[7] = f2bf(fb[ks].w);
    acc0 = __builtin_amdgcn_mfma_f32_16x16x32_bf16(a, bl[ks][0], acc0, 0, 0, 0);
    acc1 = __builtin_amdgcn_mfma_f32_16x16x32_bf16(a, bl[ks][1], acc1, 0, 0, 0);
  }

  // ---- Compute upper-K from LDS (own-staged rows; vmcnt dep only) ----
  const float* Arow = &Ahalf[lp][mt * 16 + lrow][0];
  #pragma unroll
  for (int ks = 0; ks < 8; ++ks) {
    const int c0 = ks * 8 + g * 2;               // logical 16B chunk
    float4 f0 = *(const float4*)(Arow + ((c0 ^ s) << 2));
    float4 f1 = *(const float4*)(Arow + (((c0 + 1) ^ s) << 2));
    v8s a;
    a[0] = f2bf(f0.x); a[1] = f2bf(f0.y); a[2] = f2bf(f0.z); a[3] = f2bf(f0.w);
    a[4] = f2bf(f1.x); a[5] = f2bf(f1.y); a[6] = f2bf(f1.z); a[7] = f2bf(f1.w);
    acc0 = __builtin_amdgcn_mfma_f32_16x16x32_bf16(a, bu[ks][0], acc0, 0, 0, 0);
    acc1 = __builtin_amdgcn_mfma_f32_16x16x32_bf16(a, bu[ks][1], acc1, 0, 0, 0);
  }

  __syncthreads();   // all Ahalf reads done before h1s overwrites the region

  // ---- h1 = acc + b1 -> LDS. C/D: lane l holds C[row=g*4+r][col=lrow] ----
  #pragma unroll
  for (int r = 0; r < 4; ++r) {
    const int o = mt * 16 + (g << 2) + r;
    const float bb = b1[p * 32 + o];
    h1s[lp][o][lrow] = acc0[r] + bb;
    h1s[lp][o][16 + lrow] = acc1[r] + bb;
  }
  __syncthreads();

  // ---- Layers 2+3 fp32: one thread per (position-in-block, batch) ----
  if (t < POS_PER_BLOCK * BATCH) {
    const int tp = t >> 5;
    const int b = t & 31;
    const int pg = blockIdx.x * POS_PER_BLOCK + tp;
    float h2[8];
    #pragma unroll
    for (int o8 = 0; o8 < 8; ++o8) {
      float sum = b2[pg * 8 + o8];
      const float* w2 = W2 + (size_t)(pg * 8 + o8) * 32;
      #pragma unroll
      for (int i = 0; i < 32; ++i) sum += w2[i] * h1s[tp][i][b];
      h2[o8] = sum;
    }
    #pragma unroll
    for (int c = 0; c < 3; ++c) {
      float sum = b3[pg * 3 + c];
      const float* w3 = W3 + (size_t)(pg * 3 + c) * 8;
      #pragma unroll
      for (int j = 0; j < 8; ++j) sum += w3[j] * h2[j];
      out[(size_t)(b * 3 + c) * NUM_POINTS + pg] = sum;
    }
  }
}

extern "C" void kernel_launch(void* const* d_in, const int* in_sizes, int n_in,
                              void* d_out, int out_size, void* d_ws, size_t ws_size,
                              hipStream_t stream) {
  const float* glf = (const float*)d_in[0];
  const float* W1  = (const float*)d_in[1];
  const float* b1  = (const float*)d_in[2];
  const float* W2  = (const float*)d_in[3];
  const float* b2  = (const float*)d_in[4];
  const float* W3  = (const float*)d_in[5];
  const float* b3  = (const float*)d_in[6];
  float* out = (float*)d_out;
  short* frag = (short*)d_ws;  // 32 KB of bf16 B-fragments

  hipLaunchKernelGGL(build_bfrag, dim3(64), dim3(256), 0, stream, glf, frag);
  hipLaunchKernelGGL(fcdec_main, dim3(NUM_POINTS / POS_PER_BLOCK), dim3(256), 0, stream,
                     W1, b1, W2, b2, W3, b3, frag, out);
}

// Round 9
// 31.762 us; speedup vs baseline: 1.1289x; 1.1029x over previous
//
#include <hip/hip_runtime.h>

#define NUM_POINTS 2048
#define FEAT 512
#define BATCH 32
#define POS_PER_BLOCK 2   // 2 positions x 2 M-split waves = 4 waves/block

using v8s = __attribute__((ext_vector_type(8))) short;
using v4u = __attribute__((ext_vector_type(4))) unsigned;
using v4f = __attribute__((ext_vector_type(4))) float;

// Pack bf16(x) (low16) | bf16(y) (high16) by TRUNCATION: one v_perm_b32.
// Sign-magnitude truncation -> error sign follows operand sign -> bias-free
// products; |err| <= 1 ulp. Predicted absmax ~0.06 vs threshold 0.122.
static __device__ __forceinline__ unsigned pk_trunc(float x, float y) {
  return __builtin_amdgcn_perm(__float_as_uint(y), __float_as_uint(x), 0x07060302u);
}

// R6 structure, consolidated:
//  1) issue all 16 glf float4 loads (FIRST -> retire first, in-order vmcnt)
//  2) issue A-prefetch group (16 dwordx4, ks 0..7)
//  3) build bf16 B-fragments in LDS (waits only on glf; overlaps A flight)
//  4) barrier; main loop: 8-deep rotating A refill, perm-pack converts
//  5) h1 -> LDS (aliases bfrag), 32->8->3 tail
__global__ void __launch_bounds__(256, 3) fcdec_fused(
    const float* __restrict__ glf,
    const float* __restrict__ W1, const float* __restrict__ b1,
    const float* __restrict__ W2, const float* __restrict__ b2,
    const float* __restrict__ W3, const float* __restrict__ b3,
    float* __restrict__ out) {
  __shared__ char smem[32768];
  short* bfrag = (short*)smem;                       // [16 ks][2 nt][64 l][8 j]
  float (*h1s)[32][33] = (float (*)[32][33])smem;    // aliases bfrag (after barrier)

  const int t = threadIdx.x;
  const int w = t >> 6;
  const int l = t & 63;
  const int lp = w >> 1;            // position within block
  const int mt = w & 1;             // M-split
  const int p = blockIdx.x * POS_PER_BLOCK + lp;
  const int lrow = l & 15;
  const int lk = (l >> 4) << 3;     // 0,8,16,24

  // ---- 1: glf loads first (retire earliest under in-order vmcnt) ----
  float4 g[16];
  #pragma unroll
  for (int rep = 0; rep < 16; ++rep) {
    const int c = rep * 256 + t;
    const int b = c >> 7;
    const int k0 = (c & 127) << 2;
    g[rep] = *(const float4*)(glf + b * FEAT + k0);
  }

  // ---- 2: A-prefetch group 0 (ks 0..7): 16 dwordx4 in flight ----
  const float* A0 = W1 + ((size_t)p * 32u + mt * 16 + lrow) * FEAT + lk;
  float4 fa[8], fb[8];
  #pragma unroll
  for (int kk = 0; kk < 8; ++kk) {
    fa[kk] = *(const float4*)(A0 + kk * 32);
    fb[kk] = *(const float4*)(A0 + kk * 32 + 4);
  }

  // ---- 3: build B fragments in LDS (b64 writes, perm-pack) ----
  // frag layout: lane l holds B[k=ks*32+(l>>4)*8+j][col=nt*16+(l&15)]
  #pragma unroll
  for (int rep = 0; rep < 16; ++rep) {
    const int c = rep * 256 + t;
    const int b = c >> 7;
    const int k0 = (c & 127) << 2;
    const int ks = k0 >> 5;
    const int gsel = (k0 >> 3) & 3;
    const int j0 = k0 & 7;          // 0 or 4
    const int nt = b >> 4;
    const int ll = gsel * 16 + (b & 15);
    uint2 pk;
    pk.x = pk_trunc(g[rep].x, g[rep].y);
    pk.y = pk_trunc(g[rep].z, g[rep].w);
    *(uint2*)(bfrag + (((ks * 2 + nt) * 64 + ll) << 3) + j0) = pk;
  }
  __syncthreads();

  // ---- 4: main loop: K=512, 8-deep rotating refill, 2 MFMA/ks ----
  v4f acc0 = {}, acc1 = {};
  #pragma unroll
  for (int ks = 0; ks < 16; ++ks) {
    const float4 c0 = fa[ks & 7];
    const float4 c1 = fb[ks & 7];
    if (ks < 8) {                   // static under full unroll
      fa[ks] = *(const float4*)(A0 + (ks + 8) * 32);
      fb[ks] = *(const float4*)(A0 + (ks + 8) * 32 + 4);
    }
    v4u au;
    au[0] = pk_trunc(c0.x, c0.y);
    au[1] = pk_trunc(c0.z, c0.w);
    au[2] = pk_trunc(c1.x, c1.y);
    au[3] = pk_trunc(c1.z, c1.w);
    const v8s a = __builtin_bit_cast(v8s, au);
    const v8s bv0 = *(const v8s*)(bfrag + (((ks * 2 + 0) * 64 + l) << 3));
    const v8s bv1 = *(const v8s*)(bfrag + (((ks * 2 + 1) * 64 + l) << 3));
    acc0 = __builtin_amdgcn_mfma_f32_16x16x32_bf16(a, bv0, acc0, 0, 0, 0);
    acc1 = __builtin_amdgcn_mfma_f32_16x16x32_bf16(a, bv1, acc1, 0, 0, 0);
  }

  __syncthreads();   // all bfrag reads done before h1s overwrites the region

  // ---- 5: h1 = acc + b1 -> LDS. C/D: lane l holds C[row=(l>>4)*4+r][col=l&15]
  #pragma unroll
  for (int r = 0; r < 4; ++r) {
    const int o = mt * 16 + ((l >> 4) << 2) + r;
    const float bb = b1[p * 32 + o];
    h1s[lp][o][lrow] = acc0[r] + bb;
    h1s[lp][o][16 + lrow] = acc1[r] + bb;
  }
  __syncthreads();

  // ---- Layers 2+3 fp32: one thread per (position-in-block, batch) ----
  if (t < POS_PER_BLOCK * BATCH) {
    const int tp = t >> 5;
    const int b = t & 31;
    const int pg = blockIdx.x * POS_PER_BLOCK + tp;
    float h2[8];
    #pragma unroll
    for (int o8 = 0; o8 < 8; ++o8) {
      float s = b2[pg * 8 + o8];
      const float* w2 = W2 + (size_t)(pg * 8 + o8) * 32;
      #pragma unroll
      for (int i = 0; i < 32; ++i) s += w2[i] * h1s[tp][i][b];
      h2[o8] = s;
    }
    #pragma unroll
    for (int c = 0; c < 3; ++c) {
      float s = b3[pg * 3 + c];
      const float* w3 = W3 + (size_t)(pg * 3 + c) * 8;
      #pragma unroll
      for (int j = 0; j < 8; ++j) s += w3[j] * h2[j];
      out[(size_t)(b * 3 + c) * NUM_POINTS + pg] = s;
    }
  }
}

extern "C" void kernel_launch(void* const* d_in, const int* in_sizes, int n_in,
                              void* d_out, int out_size, void* d_ws, size_t ws_size,
                              hipStream_t stream) {
  const float* glf = (const float*)d_in[0];
  const float* W1  = (const float*)d_in[1];
  const float* b1  = (const float*)d_in[2];
  const float* W2  = (const float*)d_in[3];
  const float* b2  = (const float*)d_in[4];
  const float* W3  = (const float*)d_in[5];
  const float* b3  = (const float*)d_in[6];
  float* out = (float*)d_out;

  hipLaunchKernelGGL(fcdec_fused, dim3(NUM_POINTS / POS_PER_BLOCK), dim3(256), 0, stream,
                     glf, W1, b1, W2, b2, W3, b3, out);
}

// Round 10
// 30.299 us; speedup vs baseline: 1.1834x; 1.0483x over previous
//
#include <hip/hip_runtime.h>

#define NUM_POINTS 2048
#define FEAT 512
#define BATCH 32
#define PAIRS 2               // 2 position-pairs = 4 positions per block
#define POS_PER_BLOCK 4

using v8s = __attribute__((ext_vector_type(8))) short;
using v4u = __attribute__((ext_vector_type(4))) unsigned;
using v4f = __attribute__((ext_vector_type(4))) float;

// Pack bf16(x) (low16) | bf16(y) (high16) by truncation: one v_perm_b32.
static __device__ __forceinline__ unsigned pk_trunc(float x, float y) {
  return __builtin_amdgcn_perm(__float_as_uint(y), __float_as_uint(x), 0x07060302u);
}

// Persistent-block version: 512 blocks (2/CU, zero turnover), 4 positions
// each. Rolling 8-deep A-prefetch spans the whole 32-step K-stream (2 pairs
// x 16 ks) with no drain at pair boundaries. bfrag built once per block.
// Accumulators for all 4 positions stay in registers; single epilogue.
__global__ void __launch_bounds__(256, 2) fcdec_persist(
    const float* __restrict__ glf,
    const float* __restrict__ W1, const float* __restrict__ b1,
    const float* __restrict__ W2, const float* __restrict__ b2,
    const float* __restrict__ W3, const float* __restrict__ b3,
    float* __restrict__ out) {
  __shared__ short bfrag[16 * 2 * 64 * 8];          // 32 KB, lives whole kernel
  __shared__ float h1s[POS_PER_BLOCK][32][33];      // 16.9 KB

  const int t = threadIdx.x;
  const int w = t >> 6;
  const int l = t & 63;
  const int lp = w >> 1;            // position-within-pair
  const int mt = w & 1;             // M-split
  const int lrow = l & 15;
  const int lk = (l >> 4) << 3;     // 0,8,16,24
  const int pbase = blockIdx.x * POS_PER_BLOCK;

  // Per-pair A row base pointers (this wave's 16-row slab)
  const float* Ap[PAIRS];
  #pragma unroll
  for (int pr = 0; pr < PAIRS; ++pr)
    Ap[pr] = W1 + ((size_t)(pbase + 2 * pr + lp) * 32u + mt * 16 + lrow) * FEAT + lk;

  // ---- 1: glf loads first (retire earliest under in-order vmcnt) ----
  float4 g[16];
  #pragma unroll
  for (int rep = 0; rep < 16; ++rep) {
    const int c = rep * 256 + t;
    const int b = c >> 7;
    const int k0 = (c & 127) << 2;
    g[rep] = *(const float4*)(glf + b * FEAT + k0);
  }

  // ---- 2: prologue: issue steps 0..7 (16 dwordx4 in flight) ----
  float4 fa[8], fb[8];
  #pragma unroll
  for (int s = 0; s < 8; ++s) {
    fa[s] = *(const float4*)(Ap[0] + s * 32);
    fb[s] = *(const float4*)(Ap[0] + s * 32 + 4);
  }

  // ---- 3: build B fragments in LDS once (overlaps A flight) ----
  // frag layout: lane l holds B[k=ks*32+(l>>4)*8+j][col=nt*16+(l&15)]
  #pragma unroll
  for (int rep = 0; rep < 16; ++rep) {
    const int c = rep * 256 + t;
    const int b = c >> 7;
    const int k0 = (c & 127) << 2;
    const int ks = k0 >> 5;
    const int gsel = (k0 >> 3) & 3;
    const int j0 = k0 & 7;          // 0 or 4
    const int nt = b >> 4;
    const int ll = gsel * 16 + (b & 15);
    uint2 pk;
    pk.x = pk_trunc(g[rep].x, g[rep].y);
    pk.y = pk_trunc(g[rep].z, g[rep].w);
    *(uint2*)(bfrag + (((ks * 2 + nt) * 64 + ll) << 3) + j0) = pk;
  }
  __syncthreads();

  // ---- 4: seamless main loop: 32 steps, rolling 8-deep window ----
  v4f acc[PAIRS][2] = {};
  #pragma unroll
  for (int s = 0; s < PAIRS * 16; ++s) {
    const int pr = s >> 4;
    const int ks = s & 15;
    const float4 c0 = fa[s & 7];
    const float4 c1 = fb[s & 7];
    if (s + 8 < PAIRS * 16) {       // static under full unroll
      const int s2 = s + 8;
      fa[s & 7] = *(const float4*)(Ap[s2 >> 4] + (s2 & 15) * 32);
      fb[s & 7] = *(const float4*)(Ap[s2 >> 4] + (s2 & 15) * 32 + 4);
    }
    v4u au;
    au[0] = pk_trunc(c0.x, c0.y);
    au[1] = pk_trunc(c0.z, c0.w);
    au[2] = pk_trunc(c1.x, c1.y);
    au[3] = pk_trunc(c1.z, c1.w);
    const v8s a = __builtin_bit_cast(v8s, au);
    const v8s bv0 = *(const v8s*)(bfrag + (((ks * 2 + 0) * 64 + l) << 3));
    const v8s bv1 = *(const v8s*)(bfrag + (((ks * 2 + 1) * 64 + l) << 3));
    acc[pr][0] = __builtin_amdgcn_mfma_f32_16x16x32_bf16(a, bv0, acc[pr][0], 0, 0, 0);
    acc[pr][1] = __builtin_amdgcn_mfma_f32_16x16x32_bf16(a, bv1, acc[pr][1], 0, 0, 0);
  }

  // ---- 5: h1 -> LDS for all 4 positions. C/D: row=(l>>4)*4+r, col=l&15 ----
  #pragma unroll
  for (int pr = 0; pr < PAIRS; ++pr) {
    const int pg = pbase + 2 * pr + lp;
    #pragma unroll
    for (int r = 0; r < 4; ++r) {
      const int o = mt * 16 + ((l >> 4) << 2) + r;
      const float bb = b1[pg * 32 + o];
      h1s[2 * pr + lp][o][lrow] = acc[pr][0][r] + bb;
      h1s[2 * pr + lp][o][16 + lrow] = acc[pr][1][r] + bb;
    }
  }
  __syncthreads();

  // ---- 6: layers 2+3 fp32: one thread per (position, batch) ----
  if (t < POS_PER_BLOCK * BATCH) {
    const int tp = t >> 5;          // 0..3
    const int b = t & 31;
    const int pg = pbase + tp;
    const int sp = 2 * (tp >> 1) + (tp & 1);   // h1s index == tp (identity)
    float h2[8];
    #pragma unroll
    for (int o8 = 0; o8 < 8; ++o8) {
      float s = b2[pg * 8 + o8];
      const float* w2 = W2 + (size_t)(pg * 8 + o8) * 32;
      #pragma unroll
      for (int i = 0; i < 32; ++i) s += w2[i] * h1s[sp][i][b];
      h2[o8] = s;
    }
    #pragma unroll
    for (int c = 0; c < 3; ++c) {
      float s = b3[pg * 3 + c];
      const float* w3 = W3 + (size_t)(pg * 3 + c) * 8;
      #pragma unroll
      for (int j = 0; j < 8; ++j) s += w3[j] * h2[j];
      out[(size_t)(b * 3 + c) * NUM_POINTS + pg] = s;
    }
  }
}

extern "C" void kernel_launch(void* const* d_in, const int* in_sizes, int n_in,
                              void* d_out, int out_size, void* d_ws, size_t ws_size,
                              hipStream_t stream) {
  const float* glf = (const float*)d_in[0];
  const float* W1  = (const float*)d_in[1];
  const float* b1  = (const float*)d_in[2];
  const float* W2  = (const float*)d_in[3];
  const float* b2  = (const float*)d_in[4];
  const float* W3  = (const float*)d_in[5];
  const float* b3  = (const float*)d_in[6];
  float* out = (float*)d_out;

  hipLaunchKernelGGL(fcdec_persist, dim3(NUM_POINTS / POS_PER_BLOCK), dim3(256), 0, stream,
                     glf, W1, b1, W2, b2, W3, b3, out);
}